// Round 3
// baseline (73.021 us; speedup 1.0000x reference)
//
#include <hip/hip_runtime.h>
#include <hip/hip_bf16.h>

// MemristorLinearLayer == x @ W^T + bias exactly (G_OFF/k_G/k_I all cancel).
// bf16 MFMA GEMM, M=256 N=1024 K=1024, fused fp32->bf16 conversion in staging.

typedef __attribute__((ext_vector_type(4))) float  f32x4;
typedef __attribute__((ext_vector_type(8))) short  bf16x8;

#define BATCH    256
#define SIZE_IN  1024
#define SIZE_OUT 1024

#define BM  64
#define BN  64
#define BK  64
#define LDK 72                  // padded LDS row (elems): 144B stride -> <=2-way bank conflicts
#define NT  (SIZE_IN / BK)      // 16 K-tiles

__global__ __launch_bounds__(256)
void memristor_gemm(const float* __restrict__ X, const float* __restrict__ W,
                    const float* __restrict__ bias, float* __restrict__ out) {
    __shared__ alignas(16) ushort Alds[2][BM][LDK];   // 18.4 KB
    __shared__ alignas(16) ushort Blds[2][BN][LDK];   // 18.4 KB

    const int t    = threadIdx.x;
    const int lr   = t >> 4;            // staging row-in-group 0..15
    const int lc   = (t & 15) << 2;     // staging float col 0..60
    const int brow = blockIdx.y * BM;
    const int bcol = blockIdx.x * BN;

    const int wid  = t >> 6;            // wave 0..3
    const int lane = t & 63;
    const int wr   = wid >> 1;          // wave row 0..1 (32-row sub-tile)
    const int wc   = wid & 1;           // wave col 0..1 (32-col sub-tile)
    const int fr   = lane & 15;         // fragment row/col within 16x16
    const int fg   = lane >> 4;         // k-group 0..3

    const float* Aptr = X + (size_t)(brow + lr) * SIZE_IN + lc;
    const float* Bptr = W + (size_t)(bcol + lr) * SIZE_IN + lc;

    f32x4 ar[4], br[4];

    // lambda: convert staged regs -> bf16 and write tile into LDS buffer `buf`
    auto stage = [&](int buf) {
        #pragma unroll
        for (int q = 0; q < 4; ++q) {
            union { struct { __hip_bfloat162 a, b; } h; uint2 u; } pa, pb;
            float2 f0; f0.x = ar[q].x; f0.y = ar[q].y;
            float2 f1; f1.x = ar[q].z; f1.y = ar[q].w;
            pa.h.a = __float22bfloat162_rn(f0);
            pa.h.b = __float22bfloat162_rn(f1);
            float2 g0; g0.x = br[q].x; g0.y = br[q].y;
            float2 g1; g1.x = br[q].z; g1.y = br[q].w;
            pb.h.a = __float22bfloat162_rn(g0);
            pb.h.b = __float22bfloat162_rn(g1);
            *(uint2*)&Alds[buf][lr + q * 16][lc] = pa.u;
            *(uint2*)&Blds[buf][lr + q * 16][lc] = pb.u;
        }
    };

    // prologue: load + stage K-tile 0 into buf 0
    #pragma unroll
    for (int q = 0; q < 4; ++q) {
        ar[q] = *(const f32x4*)(Aptr + q * 16 * SIZE_IN);
        br[q] = *(const f32x4*)(Bptr + q * 16 * SIZE_IN);
    }
    stage(0);
    __syncthreads();

    const f32x4 zero = {0.f, 0.f, 0.f, 0.f};
    f32x4 acc[2][2] = {{zero, zero}, {zero, zero}};

    int cur = 0;
    for (int kt = 0; kt < NT; ++kt) {
        const bool pf = (kt + 1 < NT);
        if (pf) {
            const int k = (kt + 1) * BK;
            #pragma unroll
            for (int q = 0; q < 4; ++q) {
                ar[q] = *(const f32x4*)(Aptr + q * 16 * SIZE_IN + k);
                br[q] = *(const f32x4*)(Bptr + q * 16 * SIZE_IN + k);
            }
        }
        // compute current buffer: 2 k-steps x (2x2) 16x16x32 MFMAs
        #pragma unroll
        for (int kk = 0; kk < 2; ++kk) {
            bf16x8 af[2], bfv[2];
            #pragma unroll
            for (int m = 0; m < 2; ++m)
                af[m] = *(const bf16x8*)&Alds[cur][wr * 32 + m * 16 + fr][kk * 32 + fg * 8];
            #pragma unroll
            for (int n = 0; n < 2; ++n)
                bfv[n] = *(const bf16x8*)&Blds[cur][wc * 32 + n * 16 + fr][kk * 32 + fg * 8];
            #pragma unroll
            for (int m = 0; m < 2; ++m)
                #pragma unroll
                for (int n = 0; n < 2; ++n)
                    acc[m][n] = __builtin_amdgcn_mfma_f32_16x16x32_bf16(
                        af[m], bfv[n], acc[m][n], 0, 0, 0);
        }
        if (pf) stage(cur ^ 1);
        __syncthreads();
        cur ^= 1;
    }

    // epilogue: C/D layout (verified m89): col = lane&15, row = (lane>>4)*4 + j
    #pragma unroll
    for (int n = 0; n < 2; ++n) {
        const int col = bcol + wc * 32 + n * 16 + fr;
        const float bv = bias[col];
        #pragma unroll
        for (int m = 0; m < 2; ++m) {
            const int row0 = brow + wr * 32 + m * 16 + fg * 4;
            #pragma unroll
            for (int j = 0; j < 4; ++j) {
                out[(size_t)(row0 + j) * SIZE_OUT + col] = acc[m][n][j] + bv;
            }
        }
    }
}

extern "C" void kernel_launch(void* const* d_in, const int* in_sizes, int n_in,
                              void* d_out, int out_size, void* d_ws, size_t ws_size,
                              hipStream_t stream) {
    const float* x  = (const float*)d_in[0];   // [256,1024]
    const float* w  = (const float*)d_in[1];   // [1024,1024] row-major (out,in)
    const float* b  = (const float*)d_in[2];   // [1024]
    float* out      = (float*)d_out;           // [256,1024]

    dim3 grid(SIZE_OUT / BN, BATCH / BM);      // (16, 4) = 64 blocks
    dim3 block(256);
    hipLaunchKernelGGL(memristor_gemm, grid, block, 0, stream, x, w, b, out);
}